// Round 10
// baseline (218.571 us; speedup 1.0000x reference)
//
#include <hip/hip_runtime.h>
#include <stdint.h>

// ---------------------------------------------------------------------------
// B=4, T=1024, C=1024, H=16, hs=64.
// y = samples @ V (straight-through => forward output IS the Bernoulli sample),
// att_sum = per-row sample count, att_var == 0 exactly.
// Samples reproduce JAX partitionable threefry bit-exactly:
//   bits[i] = o0 ^ o1 of threefry(fold_in(key(0),42), (0, i)).
// Attention: XCD-LOCAL WORK QUEUES. 8 queues (128 items = 8 bh x 16 qt each,
// heavy-first). Each block reads its physical XCD id (HW_REG_XCC_ID) and pulls
// from its own queue -> L2 locality guaranteed by hardware knowledge; balance
// by queue order; probe-fallback to other queues guarantees completion under
// any block->XCD placement. Inner loop = R8 (bit-exact), with the k-loop split
// into off-diagonal (branchless) and diagonal (exec-masked) passes.
// ---------------------------------------------------------------------------

#define T_SEQ 1024
#define QKV_LD 3072
#define ATTN_GRID 768

typedef __attribute__((ext_vector_type(8))) short bf16x8;
typedef __attribute__((ext_vector_type(4))) float f32x4;
typedef __attribute__((ext_vector_type(4))) unsigned int u32x4;

typedef __attribute__((address_space(3))) uint32_t lds_u32;
typedef __attribute__((address_space(1))) const uint32_t g_u32;

#define ROTL(x, d) __builtin_amdgcn_alignbit((x), (x), 32 - (d))

__device__ __forceinline__ void threefry2x32(uint32_t k0, uint32_t k1,
                                             uint32_t x0, uint32_t x1,
                                             uint32_t &o0, uint32_t &o1) {
  uint32_t ks2 = k0 ^ k1 ^ 0x1BD11BDAu;
#define TF_R4(a, b, c, d)                                                      \
  x0 += x1; x1 = ROTL(x1, a); x1 ^= x0;                                        \
  x0 += x1; x1 = ROTL(x1, b); x1 ^= x0;                                        \
  x0 += x1; x1 = ROTL(x1, c); x1 ^= x0;                                        \
  x0 += x1; x1 = ROTL(x1, d); x1 ^= x0;
  x0 += k0; x1 += k1;
  TF_R4(13, 15, 26, 6)
  x0 += k1; x1 += ks2 + 1u;
  TF_R4(17, 29, 16, 24)
  x0 += ks2; x1 += k0 + 2u;
  TF_R4(13, 15, 26, 6)
  x0 += k0; x1 += k1 + 3u;
  TF_R4(17, 29, 16, 24)
  x0 += k1; x1 += ks2 + 4u;
  TF_R4(13, 15, 26, 6)
  x0 += ks2; x1 += k0 + 5u;
  o0 = x0; o1 = x1;
#undef TF_R4
}

__device__ __forceinline__ unsigned short f2bf(float f) {  // RNE
  uint32_t u = __float_as_uint(f);
  u += 0x7FFFu + ((u >> 16) & 1u);
  return (unsigned short)(u >> 16);
}

// ---------------------------------------------------------------------------
// Fused f32->bf16 conversion of x, w_attn, w_proj (outputs contiguous in ws).
// ---------------------------------------------------------------------------
#define N_X4  1048576   // 4M f32 / 4
#define N_WA4 786432    // 3M / 4
#define N_WP4 262144    // 1M / 4

__global__ __launch_bounds__(256) void cvt3_bf16(const float4* __restrict__ x,
                                                 const float4* __restrict__ wa,
                                                 const float4* __restrict__ wp,
                                                 uint2* __restrict__ out) {
  size_t i = (size_t)blockIdx.x * 256 + threadIdx.x;
  const float4* src;
  size_t off;
  if (i < N_X4) { src = x; off = i; }
  else if (i < N_X4 + N_WA4) { src = wa; off = i - N_X4; }
  else { src = wp; off = i - (N_X4 + N_WA4); }
  float4 v = src[off];
  uint2 o;
  o.x = (uint32_t)f2bf(v.x) | ((uint32_t)f2bf(v.y) << 16);
  o.y = (uint32_t)f2bf(v.z) | ((uint32_t)f2bf(v.w) << 16);
  out[i] = o;
}

__global__ void init_ctr(uint32_t* __restrict__ ctr) {
  if (threadIdx.x < 8) ctr[threadIdx.x] = 0u;
}

// ---------------------------------------------------------------------------
// bf16 MFMA GEMM: C[M,N] = A[M,K] @ B[N,K]^T. 128x128 tile, BK=32, 4 waves.
// m97 structure: global_load_lds width-16 into LINEAR LDS [row][32 bf16].
// ---------------------------------------------------------------------------
template <int OUT_BF16>
__global__ __launch_bounds__(256) void gemm_bf16(const unsigned short* __restrict__ A,
                                                 const unsigned short* __restrict__ B,
                                                 void* __restrict__ Cout,
                                                 int M, int N, int K) {
  __shared__ unsigned short As[128 * 32];  // 8 KB, linear
  __shared__ unsigned short Bs[128 * 32];

  const int t = threadIdx.x;
  const int lane = t & 63, w = t >> 6;
  const int g = lane >> 4, lr = lane & 15;
  const int rw = w >> 1, cw = w & 1;
  const int bm = blockIdx.x * 128, bn = blockIdx.y * 128;

  const unsigned short* Ag = A + (size_t)(bm + 32 * w + (lane >> 2)) * K + 8 * (lane & 3);
  const unsigned short* Bg = B + (size_t)(bn + 32 * w + (lane >> 2)) * K + 8 * (lane & 3);
  lds_u32* Al0 = (lds_u32*)&As[(32 * w) * 32];
  lds_u32* Al1 = (lds_u32*)&As[(32 * w + 16) * 32];
  lds_u32* Bl0 = (lds_u32*)&Bs[(32 * w) * 32];
  lds_u32* Bl1 = (lds_u32*)&Bs[(32 * w + 16) * 32];

  f32x4 acc[4][4];
#pragma unroll
  for (int i = 0; i < 4; ++i)
#pragma unroll
    for (int j = 0; j < 4; ++j) acc[i][j] = (f32x4){0.f, 0.f, 0.f, 0.f};

  for (int k0 = 0; k0 < K; k0 += 32) {
    __syncthreads();
    __builtin_amdgcn_global_load_lds((g_u32*)(const void*)(Ag + k0), Al0, 16, 0, 0);
    __builtin_amdgcn_global_load_lds((g_u32*)(const void*)(Ag + k0 + (size_t)16 * K), Al1, 16, 0, 0);
    __builtin_amdgcn_global_load_lds((g_u32*)(const void*)(Bg + k0), Bl0, 16, 0, 0);
    __builtin_amdgcn_global_load_lds((g_u32*)(const void*)(Bg + k0 + (size_t)16 * K), Bl1, 16, 0, 0);
    __syncthreads();

    bf16x8 af[4], bfr[4];
#pragma unroll
    for (int i = 0; i < 4; ++i)
      af[i] = *(const bf16x8*)&As[(64 * rw + 16 * i + lr) * 32 + 8 * g];
#pragma unroll
    for (int j = 0; j < 4; ++j)
      bfr[j] = *(const bf16x8*)&Bs[(64 * cw + 16 * j + lr) * 32 + 8 * g];
#pragma unroll
    for (int i = 0; i < 4; ++i)
#pragma unroll
      for (int j = 0; j < 4; ++j)
        acc[i][j] = __builtin_amdgcn_mfma_f32_16x16x32_bf16(af[i], bfr[j], acc[i][j], 0, 0, 0);
  }

#pragma unroll
  for (int i = 0; i < 4; ++i)
#pragma unroll
    for (int j = 0; j < 4; ++j)
#pragma unroll
      for (int r = 0; r < 4; ++r) {
        const size_t row = bm + 64 * rw + 16 * i + 4 * g + r;
        const size_t col = bn + 64 * cw + 16 * j + lr;
        if (OUT_BF16)
          ((unsigned short*)Cout)[row * N + col] = f2bf(acc[i][j][r]);
        else
          ((float*)Cout)[row * N + col] = acc[i][j][r];
      }
}

// ---------------------------------------------------------------------------
// XCD-queue tiled MFMA attention + exact threefry Bernoulli sampling.
// Queue item idx in [0,128): bh = 8*xcd + (idx&7), qt = 15 - (idx>>3).
// Block = 4 waves; wave w owns q rows [qt*64+16w, +16). LDS 25.6KB.
// ---------------------------------------------------------------------------
// MASKED=1 only for the diagonal k-tile; off-diagonal tiles skip the causal
// test entirely (kg <= kt*64+63 < qt*64 <= qg always).
#define SAMPLE_PASS(MASKED)                                                    \
  for (int c = 0; c < 4; ++c) {                                                \
    const uint32_t* krow = &Ks4[(16 * c + lr) * 32];                           \
    bf16x8 bk0 = *(const bf16x8*)&krow[(4 * g) ^ swzr];                        \
    bf16x8 bk1 = *(const bf16x8*)&krow[(4 * g + 16) ^ swzr];                   \
    f32x4 sa = __builtin_amdgcn_mfma_f32_16x16x32_bf16(                        \
        aq0, bk0, (f32x4){0.f, 0.f, 0.f, 0.f}, 0, 0, 0);                       \
    sa = __builtin_amdgcn_mfma_f32_16x16x32_bf16(aq1, bk1, sa, 0, 0, 0);       \
    const int kg = kt64 + 16 * c + lr;                                         \
    _Pragma("unroll")                                                          \
    for (int r = 0; r < 4; ++r) {                                              \
      const int qg = q0 + 4 * g + r;                                           \
      unsigned short sbits = 0;                                                \
      if (!MASKED || kg <= qg) {                                               \
        float e = __builtin_exp2f(sa[r] * -0.18033688011112042f);              \
        uint32_t idx2 = ((uint32_t)bh << 20) | ((uint32_t)qg << 10) | (uint32_t)kg; \
        uint32_t r0, r1;                                                       \
        threefry2x32(dk0, dk1, 0u, idx2, r0, r1);                              \
        float u = __uint_as_float(0x3F800000u | ((r0 ^ r1) >> 9)) - 1.0f;      \
        if (fmaf(u, e, u) < 1.0f) { sbits = 0x3F80; rs[r] += 1; }              \
      }                                                                        \
      stw[4 * g + r][16 * c + lr] = sbits;                                     \
    }                                                                          \
  }

__global__ __launch_bounds__(256) void attn_queue(const unsigned short* __restrict__ qkv,
                                                  unsigned short* __restrict__ yatt,
                                                  float* __restrict__ att_sum,
                                                  float* __restrict__ att_var,
                                                  uint32_t* __restrict__ qctr) {
  __shared__ uint32_t Ks4[64 * 32];         // 8 KB
  __shared__ uint32_t Vt4[64 * 32];         // 8 KB
  __shared__ unsigned short St[4][16][72];  // 9.2 KB, wave-private strips
  __shared__ int s_item, s_xcc;

  const int t = threadIdx.x;
  const int lane = t & 63, w = t >> 6;
  const int g = lane >> 4, lr = lane & 15;

  uint32_t my_xcc;
  asm volatile("s_getreg_b32 %0, hwreg(HW_REG_XCC_ID)" : "=s"(my_xcc));
  my_xcc &= 7u;

  uint32_t dk0, dk1;  // fold_in(key(0), 42)
  threefry2x32(0u, 0u, 0u, 42u, dk0, dk1);

  const int swzr = (lr & 7) << 2;
  unsigned short (*stw)[72] = St[w];

  int probe = 0;  // thread 0's persistent queue cursor
  for (;;) {
    __syncthreads();  // prior item's LDS reads complete; protect s_item
    if (t == 0) {
      int got = -1, gx = 0;
      while (probe < 8) {
        int x = ((int)my_xcc + probe) & 7;
        uint32_t idx = atomicAdd(&qctr[x], 1u);
        if (idx < 128u) { got = (int)idx; gx = x; break; }
        ++probe;  // queue x exhausted forever (monotonic counter)
      }
      s_item = got; s_xcc = gx;
    }
    __syncthreads();
    const int item = s_item;
    if (item < 0) break;
    const int bh = 8 * s_xcc + (item & 7);
    const int qt = 15 - (item >> 3);  // heavy-first
    const int b = bh >> 4, h = bh & 15;
    const int qt64 = qt * 64;
    const int q0 = qt64 + 16 * w;

    // ---- Q A-frags direct from global ----
    const unsigned short* qr = qkv + (size_t)(b * T_SEQ + q0 + lr) * QKV_LD + h * 64 + 8 * g;
    const bf16x8 aq0 = *(const bf16x8*)qr;
    const bf16x8 aq1 = *(const bf16x8*)(qr + 32);

    f32x4 yacc[4];
#pragma unroll
    for (int c = 0; c < 4; ++c) yacc[c] = (f32x4){0.f, 0.f, 0.f, 0.f};
    int rs[4] = {0, 0, 0, 0};

#pragma unroll 1
    for (int kt = 0; kt <= qt; ++kt) {
      __syncthreads();  // prev Ks/Vt reads complete
      // ---- stage K tile (coalesced, swizzled) ----
      const unsigned short* kb = qkv + (size_t)(b * T_SEQ + kt * 64) * QKV_LD + 1024 + h * 64;
      {
        const int r = t >> 2, s4 = t & 3;
        const unsigned short* src = kb + (size_t)r * QKV_LD + 8 * s4;
        u32x4 v0 = *(const u32x4*)(src);
        u32x4 v1 = *(const u32x4*)(src + 32);
        const int sw = (r & 7) << 2;
        *(u32x4*)&Ks4[r * 32 + ((4 * s4) ^ sw)] = v0;
        *(u32x4*)&Ks4[r * 32 + ((4 * s4 + 16) ^ sw)] = v1;
      }
      // ---- stage V transposed: Vt[d][k] ----
      {
        const int k2 = 2 * (t & 31), d0 = 8 * (t >> 5);
        const unsigned short* vsrc =
            qkv + (size_t)(b * T_SEQ + kt * 64 + k2) * QKV_LD + 2048 + h * 64 + d0;
        union { u32x4 v; unsigned short us[8]; } va, vb2;
        va.v = *(const u32x4*)(vsrc);
        vb2.v = *(const u32x4*)(vsrc + QKV_LD);
#pragma unroll
        for (int jj = 0; jj < 8; ++jj) {
          uint32_t pw = (uint32_t)va.us[jj] | ((uint32_t)vb2.us[jj] << 16);
          Vt4[(d0 + jj) * 32 + ((t & 31) ^ ((jj & 7) << 2))] = pw;
        }
      }
      __syncthreads();

      // ---- QK^T + sigmoid + threefry sample ----
      const int kt64 = kt * 64;
      if (kt < qt) {
#pragma unroll
        SAMPLE_PASS(0)
      } else {
#pragma unroll
        SAMPLE_PASS(1)
      }
      // St rows are wave-private: same-wave LDS dep, no barrier.

      // ---- Y += P @ V ----
#pragma unroll
      for (int ks = 0; ks < 2; ++ks) {
        const bf16x8 pa = *(const bf16x8*)&stw[lr][32 * ks + 8 * g];
#pragma unroll
        for (int c = 0; c < 4; ++c) {
          bf16x8 vb = *(const bf16x8*)&Vt4[(16 * c + lr) * 32 + ((4 * g + 16 * ks) ^ swzr)];
          yacc[c] = __builtin_amdgcn_mfma_f32_16x16x32_bf16(pa, vb, yacc[c], 0, 0, 0);
        }
      }
    }

    // ---- item epilogue: yatt (bf16), att_sum, att_var ----
    const size_t yb = (size_t)(b * T_SEQ + q0) * 1024 + h * 64;
#pragma unroll
    for (int c = 0; c < 4; ++c)
#pragma unroll
      for (int r = 0; r < 4; ++r)
        yatt[yb + (size_t)(4 * g + r) * 1024 + 16 * c + lr] = f2bf(yacc[c][r]);

#pragma unroll
    for (int r = 0; r < 4; ++r) {
      rs[r] += __shfl_xor(rs[r], 1);
      rs[r] += __shfl_xor(rs[r], 2);
      rs[r] += __shfl_xor(rs[r], 4);
      rs[r] += __shfl_xor(rs[r], 8);
    }
    if (lr == 0) {
#pragma unroll
      for (int r = 0; r < 4; ++r)
        att_sum[(size_t)bh * T_SEQ + q0 + 4 * g + r] = (float)rs[r];
    }
    if (lane < 16) att_var[(size_t)bh * T_SEQ + q0 + lane] = 0.f;  // s*(1-s)==0
  }
}

extern "C" void kernel_launch(void* const* d_in, const int* in_sizes, int n_in,
                              void* d_out, int out_size, void* d_ws, size_t ws_size,
                              hipStream_t stream) {
  (void)in_sizes; (void)n_in; (void)out_size; (void)ws_size;
  const float* x      = (const float*)d_in[0];  // [4,1024,1024]
  const float* w_attn = (const float*)d_in[1];  // [3072,1024]
  const float* w_proj = (const float*)d_in[2];  // [1024,1024]

  float* y_out      = (float*)d_out;                    // [4,1024,1024] f32
  float* attsum_out = y_out + (size_t)4 * 1024 * 1024;  // [4,16,1024]
  float* attvar_out = attsum_out + (size_t)4 * 16 * 1024;

  unsigned short* ws_us = (unsigned short*)d_ws;
  unsigned short* x_bf    = ws_us;                             // 4M elems
  unsigned short* wa_bf   = x_bf + (size_t)4 * 1024 * 1024;    // 3M
  unsigned short* wp_bf   = wa_bf + (size_t)3 * 1024 * 1024;   // 1M
  unsigned short* qkv_bf  = wp_bf + (size_t)1024 * 1024;       // 12M
  unsigned short* yatt_bf = qkv_bf + (size_t)4096 * 3072;      // 4M
  uint32_t* qctr = (uint32_t*)(yatt_bf + (size_t)4096 * 1024); // 8 u32

  dim3 blk(256);
  init_ctr<<<dim3(1), dim3(64), 0, stream>>>(qctr);
  cvt3_bf16<<<dim3(8192), blk, 0, stream>>>((const float4*)x, (const float4*)w_attn,
                                            (const float4*)w_proj, (uint2*)x_bf);
  gemm_bf16<1><<<dim3(32, 24), blk, 0, stream>>>(x_bf, wa_bf, (void*)qkv_bf, 4096, 3072, 1024);
  attn_queue<<<dim3(ATTN_GRID), blk, 0, stream>>>(qkv_bf, yatt_bf, attsum_out,
                                                  attvar_out, qctr);
  gemm_bf16<0><<<dim3(32, 8), blk, 0, stream>>>(yatt_bf, wp_bf, (void*)y_out, 4096, 1024, 1024);
}

// Round 11
// 171.362 us; speedup vs baseline: 1.2755x; 1.2755x over previous
//
#include <hip/hip_runtime.h>
#include <stdint.h>

// ---------------------------------------------------------------------------
// B=4, T=1024, C=1024, H=16, hs=64.
// y = samples @ V (straight-through => forward output IS the Bernoulli sample),
// att_sum = per-row sample count (popcount), att_var == 0 exactly.
// Samples reproduce JAX partitionable threefry bit-exactly:
//   bits[i] = o0 ^ o1 of threefry(fold_in(key(0),42), (0, i)).
// Attention in TWO kernels:
//   A attn_sample: 8704 IDENTICAL blocks (bh x lower-tri (qt,kt) 64x64 tiles):
//     QK^T -> sigmoid -> threefry -> ballot-packed bitmask Pbits. Perfect
//     balance by construction; 8KB LDS; no V, no PV, no atomics.
//   B attn_pv: y = P@V expanding bits -> bf16 frags (MFMA order identical to
//     the fused version => bit-identical y); att_sum = popcount; att_var = 0.
// ---------------------------------------------------------------------------

#define T_SEQ 1024
#define QKV_LD 3072

typedef __attribute__((ext_vector_type(8))) short bf16x8;
typedef __attribute__((ext_vector_type(4))) float f32x4;
typedef __attribute__((ext_vector_type(4))) unsigned int u32x4;

typedef __attribute__((address_space(3))) uint32_t lds_u32;
typedef __attribute__((address_space(1))) const uint32_t g_u32;

#define ROTL(x, d) __builtin_amdgcn_alignbit((x), (x), 32 - (d))

__device__ __forceinline__ void threefry2x32(uint32_t k0, uint32_t k1,
                                             uint32_t x0, uint32_t x1,
                                             uint32_t &o0, uint32_t &o1) {
  uint32_t ks2 = k0 ^ k1 ^ 0x1BD11BDAu;
#define TF_R4(a, b, c, d)                                                      \
  x0 += x1; x1 = ROTL(x1, a); x1 ^= x0;                                        \
  x0 += x1; x1 = ROTL(x1, b); x1 ^= x0;                                        \
  x0 += x1; x1 = ROTL(x1, c); x1 ^= x0;                                        \
  x0 += x1; x1 = ROTL(x1, d); x1 ^= x0;
  x0 += k0; x1 += k1;
  TF_R4(13, 15, 26, 6)
  x0 += k1; x1 += ks2 + 1u;
  TF_R4(17, 29, 16, 24)
  x0 += ks2; x1 += k0 + 2u;
  TF_R4(13, 15, 26, 6)
  x0 += k0; x1 += k1 + 3u;
  TF_R4(17, 29, 16, 24)
  x0 += k1; x1 += ks2 + 4u;
  TF_R4(13, 15, 26, 6)
  x0 += ks2; x1 += k0 + 5u;
  o0 = x0; o1 = x1;
#undef TF_R4
}

__device__ __forceinline__ unsigned short f2bf(float f) {  // RNE
  uint32_t u = __float_as_uint(f);
  u += 0x7FFFu + ((u >> 16) & 1u);
  return (unsigned short)(u >> 16);
}

// ---------------------------------------------------------------------------
// Fused f32->bf16 conversion of x, w_attn, w_proj (outputs contiguous in ws).
// ---------------------------------------------------------------------------
#define N_X4  1048576   // 4M f32 / 4
#define N_WA4 786432    // 3M / 4
#define N_WP4 262144    // 1M / 4

__global__ __launch_bounds__(256) void cvt3_bf16(const float4* __restrict__ x,
                                                 const float4* __restrict__ wa,
                                                 const float4* __restrict__ wp,
                                                 uint2* __restrict__ out) {
  size_t i = (size_t)blockIdx.x * 256 + threadIdx.x;
  const float4* src;
  size_t off;
  if (i < N_X4) { src = x; off = i; }
  else if (i < N_X4 + N_WA4) { src = wa; off = i - N_X4; }
  else { src = wp; off = i - (N_X4 + N_WA4); }
  float4 v = src[off];
  uint2 o;
  o.x = (uint32_t)f2bf(v.x) | ((uint32_t)f2bf(v.y) << 16);
  o.y = (uint32_t)f2bf(v.z) | ((uint32_t)f2bf(v.w) << 16);
  out[i] = o;
}

// ---------------------------------------------------------------------------
// bf16 MFMA GEMM: C[M,N] = A[M,K] @ B[N,K]^T. 128x128 tile, BK=32, 4 waves.
// m97 structure: global_load_lds width-16 into LINEAR LDS [row][32 bf16].
// ---------------------------------------------------------------------------
template <int OUT_BF16>
__global__ __launch_bounds__(256) void gemm_bf16(const unsigned short* __restrict__ A,
                                                 const unsigned short* __restrict__ B,
                                                 void* __restrict__ Cout,
                                                 int M, int N, int K) {
  __shared__ unsigned short As[128 * 32];  // 8 KB, linear
  __shared__ unsigned short Bs[128 * 32];

  const int t = threadIdx.x;
  const int lane = t & 63, w = t >> 6;
  const int g = lane >> 4, lr = lane & 15;
  const int rw = w >> 1, cw = w & 1;
  const int bm = blockIdx.x * 128, bn = blockIdx.y * 128;

  const unsigned short* Ag = A + (size_t)(bm + 32 * w + (lane >> 2)) * K + 8 * (lane & 3);
  const unsigned short* Bg = B + (size_t)(bn + 32 * w + (lane >> 2)) * K + 8 * (lane & 3);
  lds_u32* Al0 = (lds_u32*)&As[(32 * w) * 32];
  lds_u32* Al1 = (lds_u32*)&As[(32 * w + 16) * 32];
  lds_u32* Bl0 = (lds_u32*)&Bs[(32 * w) * 32];
  lds_u32* Bl1 = (lds_u32*)&Bs[(32 * w + 16) * 32];

  f32x4 acc[4][4];
#pragma unroll
  for (int i = 0; i < 4; ++i)
#pragma unroll
    for (int j = 0; j < 4; ++j) acc[i][j] = (f32x4){0.f, 0.f, 0.f, 0.f};

  for (int k0 = 0; k0 < K; k0 += 32) {
    __syncthreads();
    __builtin_amdgcn_global_load_lds((g_u32*)(const void*)(Ag + k0), Al0, 16, 0, 0);
    __builtin_amdgcn_global_load_lds((g_u32*)(const void*)(Ag + k0 + (size_t)16 * K), Al1, 16, 0, 0);
    __builtin_amdgcn_global_load_lds((g_u32*)(const void*)(Bg + k0), Bl0, 16, 0, 0);
    __builtin_amdgcn_global_load_lds((g_u32*)(const void*)(Bg + k0 + (size_t)16 * K), Bl1, 16, 0, 0);
    __syncthreads();

    bf16x8 af[4], bfr[4];
#pragma unroll
    for (int i = 0; i < 4; ++i)
      af[i] = *(const bf16x8*)&As[(64 * rw + 16 * i + lr) * 32 + 8 * g];
#pragma unroll
    for (int j = 0; j < 4; ++j)
      bfr[j] = *(const bf16x8*)&Bs[(64 * cw + 16 * j + lr) * 32 + 8 * g];
#pragma unroll
    for (int i = 0; i < 4; ++i)
#pragma unroll
      for (int j = 0; j < 4; ++j)
        acc[i][j] = __builtin_amdgcn_mfma_f32_16x16x32_bf16(af[i], bfr[j], acc[i][j], 0, 0, 0);
  }

#pragma unroll
  for (int i = 0; i < 4; ++i)
#pragma unroll
    for (int j = 0; j < 4; ++j)
#pragma unroll
      for (int r = 0; r < 4; ++r) {
        const size_t row = bm + 64 * rw + 16 * i + 4 * g + r;
        const size_t col = bn + 64 * cw + 16 * j + lr;
        if (OUT_BF16)
          ((unsigned short*)Cout)[row * N + col] = f2bf(acc[i][j][r]);
        else
          ((float*)Cout)[row * N + col] = acc[i][j][r];
      }
}

// ---------------------------------------------------------------------------
// Kernel A: score-tile sampler. 8704 identical blocks.
// bid -> bh = 8*(bid&7)+((bid>>3)&7) (XCD-affine), id136 = bid>>6,
// qt = QT_OF[id136], kt = id136 - qt(qt+1)/2.
// Per block: stage K tile (8KB), Q frags direct, QK^T MFMA, sigmoid+threefry,
// ballot-pack samples into Pbits[bh][q][k/16] u16.
// ---------------------------------------------------------------------------
__constant__ uint8_t QT_OF[136] = {
    0, 1, 1, 2, 2, 2, 3, 3, 3, 3, 4, 4, 4, 4, 4, 5, 5, 5, 5, 5, 5,
    6, 6, 6, 6, 6, 6, 6, 7, 7, 7, 7, 7, 7, 7, 7,
    8, 8, 8, 8, 8, 8, 8, 8, 8, 9, 9, 9, 9, 9, 9, 9, 9, 9, 9,
    10, 10, 10, 10, 10, 10, 10, 10, 10, 10, 10,
    11, 11, 11, 11, 11, 11, 11, 11, 11, 11, 11, 11,
    12, 12, 12, 12, 12, 12, 12, 12, 12, 12, 12, 12, 12,
    13, 13, 13, 13, 13, 13, 13, 13, 13, 13, 13, 13, 13, 13,
    14, 14, 14, 14, 14, 14, 14, 14, 14, 14, 14, 14, 14, 14, 14,
    15, 15, 15, 15, 15, 15, 15, 15, 15, 15, 15, 15, 15, 15, 15, 15};

__global__ __launch_bounds__(256, 6) void attn_sample(const unsigned short* __restrict__ qkv,
                                                      unsigned short* __restrict__ Pbits) {
  __shared__ uint32_t Ks4[64 * 32];  // 8 KB

  const int t = threadIdx.x;
  const int lane = t & 63, w = t >> 6;
  const int g = lane >> 4, lr = lane & 15;
  const int bid = blockIdx.x;                   // 0..8703
  const int bh = 8 * (bid & 7) + ((bid >> 3) & 7);
  const int id = bid >> 6;                      // 0..135
  const int qt = QT_OF[id];
  const int kt = id - ((qt * (qt + 1)) >> 1);
  const int b = bh >> 4, h = bh & 15;
  const int q0 = qt * 64 + 16 * w;
  const int kt64 = kt * 64;
  const bool diag = (kt == qt);

  uint32_t dk0, dk1;  // fold_in(key(0), 42)
  threefry2x32(0u, 0u, 0u, 42u, dk0, dk1);

  // ---- stage K tile (coalesced, swizzled) ----
  const unsigned short* kb = qkv + (size_t)(b * T_SEQ + kt64) * QKV_LD + 1024 + h * 64;
  {
    const int r = t >> 2, s4 = t & 3;
    const unsigned short* src = kb + (size_t)r * QKV_LD + 8 * s4;
    u32x4 v0 = *(const u32x4*)(src);
    u32x4 v1 = *(const u32x4*)(src + 32);
    const int sw = (r & 7) << 2;
    *(u32x4*)&Ks4[r * 32 + ((4 * s4) ^ sw)] = v0;
    *(u32x4*)&Ks4[r * 32 + ((4 * s4 + 16) ^ sw)] = v1;
  }
  // ---- Q A-frags direct from global ----
  const unsigned short* qr = qkv + (size_t)(b * T_SEQ + q0 + lr) * QKV_LD + h * 64 + 8 * g;
  const bf16x8 aq0 = *(const bf16x8*)qr;
  const bf16x8 aq1 = *(const bf16x8*)(qr + 32);
  __syncthreads();

  const int swzr = (lr & 7) << 2;
  unsigned short* prow = Pbits + ((size_t)((bh << 10) + q0)) * 64 + kt * 4;

#pragma unroll
  for (int c = 0; c < 4; ++c) {
    const uint32_t* krow = &Ks4[(16 * c + lr) * 32];
    bf16x8 bk0 = *(const bf16x8*)&krow[(4 * g) ^ swzr];
    bf16x8 bk1 = *(const bf16x8*)&krow[(4 * g + 16) ^ swzr];
    f32x4 sa = __builtin_amdgcn_mfma_f32_16x16x32_bf16(aq0, bk0, (f32x4){0.f, 0.f, 0.f, 0.f}, 0, 0, 0);
    sa = __builtin_amdgcn_mfma_f32_16x16x32_bf16(aq1, bk1, sa, 0, 0, 0);

    const int kg = kt64 + 16 * c + lr;
#pragma unroll
    for (int r = 0; r < 4; ++r) {
      const int qg = q0 + 4 * g + r;
      bool pred = false;
      if (!diag || kg <= qg) {  // whole-wave-false chunks skip via execz
        float e = __builtin_exp2f(sa[r] * -0.18033688011112042f);
        uint32_t idx2 = ((uint32_t)bh << 20) | ((uint32_t)qg << 10) | (uint32_t)kg;
        uint32_t r0, r1;
        threefry2x32(dk0, dk1, 0u, idx2, r0, r1);
        float u = __uint_as_float(0x3F800000u | ((r0 ^ r1) >> 9)) - 1.0f;
        pred = (fmaf(u, e, u) < 1.0f);  // u(1+e) < 1
      }
      unsigned long long m = __ballot(pred);
      if (lr == 0)  // 4 lanes (one per g) store their row's 16 bits
        prow[(size_t)(4 * g + r) * 64 + c] = (unsigned short)((m >> (16 * g)) & 0xFFFFu);
    }
  }
}

// ---------------------------------------------------------------------------
// Kernel B: PV from bitmask. Block = (bh, qt); 1024 blocks x 4 waves.
// Wave w: rows [qt*64+16w, +16). Per k-step: stage V transposed (8KB LDS),
// lane reads its row's 64 sample bits (u64), expands 8-bit groups to bf16x8
// A-frags; MFMA order identical to fused version -> bit-identical y.
// att_sum = popcount(row bits); att_var = 0.
// ---------------------------------------------------------------------------
__global__ __launch_bounds__(256) void attn_pv(const unsigned short* __restrict__ qkv,
                                               const unsigned short* __restrict__ Pbits,
                                               unsigned short* __restrict__ yatt,
                                               float* __restrict__ att_sum,
                                               float* __restrict__ att_var) {
  __shared__ uint32_t Vt4[64 * 32];  // 8 KB

  const int t = threadIdx.x;
  const int lane = t & 63, w = t >> 6;
  const int g = lane >> 4, lr = lane & 15;
  const int bid = blockIdx.x;                   // 0..1023
  const int bh = 8 * (bid & 7) + ((bid >> 3) & 7);
  const int qt = 15 - (bid >> 6);               // heavy-first
  const int b = bh >> 4, h = bh & 15;
  const int q0 = qt * 64 + 16 * w;

  const int swzr = (lr & 7) << 2;
  const unsigned short* prow = Pbits + ((size_t)((bh << 10) + q0 + lr)) * 64;

  f32x4 yacc[4];
#pragma unroll
  for (int c = 0; c < 4; ++c) yacc[c] = (f32x4){0.f, 0.f, 0.f, 0.f};
  uint32_t rs = 0;

#pragma unroll 1
  for (int kt = 0; kt <= qt; ++kt) {
    __syncthreads();  // prev Vt reads complete
    // ---- stage V transposed: Vt[d][k] ----
    {
      const int k2 = 2 * (t & 31), d0 = 8 * (t >> 5);
      const unsigned short* vsrc =
          qkv + (size_t)(b * T_SEQ + kt * 64 + k2) * QKV_LD + 2048 + h * 64 + d0;
      union { u32x4 v; unsigned short us[8]; } va, vb2;
      va.v = *(const u32x4*)(vsrc);
      vb2.v = *(const u32x4*)(vsrc + QKV_LD);
#pragma unroll
      for (int jj = 0; jj < 8; ++jj) {
        uint32_t pw = (uint32_t)va.us[jj] | ((uint32_t)vb2.us[jj] << 16);
        Vt4[(d0 + jj) * 32 + ((t & 31) ^ ((jj & 7) << 2))] = pw;
      }
    }
    __syncthreads();

    // ---- this row's 64 sample bits for the k-step ----
    const uint64_t bits = *(const uint64_t*)(prow + kt * 4);
    rs += (uint32_t)__popcll(bits);  // same value across g; only g==0 writes

    // ---- Y += P @ V (bit-expand A-frags; order identical to fused) ----
#pragma unroll
    for (int ks = 0; ks < 2; ++ks) {
      const uint32_t byte = (uint32_t)(bits >> (32 * ks + 8 * g)) & 0xFFu;
      union { uint32_t u[4]; bf16x8 v; } pa;
#pragma unroll
      for (int j = 0; j < 4; ++j) {
        pa.u[j] = ((byte >> (2 * j)) & 1u ? 0x3F80u : 0u) |
                  ((byte >> (2 * j + 1)) & 1u ? 0x3F800000u : 0u);
      }
#pragma unroll
      for (int c = 0; c < 4; ++c) {
        bf16x8 vb = *(const bf16x8*)&Vt4[(16 * c + lr) * 32 + ((4 * g + 16 * ks) ^ swzr)];
        yacc[c] = __builtin_amdgcn_mfma_f32_16x16x32_bf16(pa.v, vb, yacc[c], 0, 0, 0);
      }
    }
  }

  // ---- epilogue: yatt (bf16), att_sum, att_var ----
  const size_t yb = (size_t)(b * T_SEQ + q0) * 1024 + h * 64;
#pragma unroll
  for (int c = 0; c < 4; ++c)
#pragma unroll
    for (int r = 0; r < 4; ++r)
      yatt[yb + (size_t)(4 * g + r) * 1024 + 16 * c + lr] = f2bf(yacc[c][r]);

  if (g == 0) att_sum[(size_t)bh * T_SEQ + q0 + lr] = (float)rs;
  if (lane < 16) att_var[(size_t)bh * T_SEQ + q0 + lane] = 0.f;  // s*(1-s)==0
}

extern "C" void kernel_launch(void* const* d_in, const int* in_sizes, int n_in,
                              void* d_out, int out_size, void* d_ws, size_t ws_size,
                              hipStream_t stream) {
  (void)in_sizes; (void)n_in; (void)out_size; (void)ws_size;
  const float* x      = (const float*)d_in[0];  // [4,1024,1024]
  const float* w_attn = (const float*)d_in[1];  // [3072,1024]
  const float* w_proj = (const float*)d_in[2];  // [1024,1024]

  float* y_out      = (float*)d_out;                    // [4,1024,1024] f32
  float* attsum_out = y_out + (size_t)4 * 1024 * 1024;  // [4,16,1024]
  float* attvar_out = attsum_out + (size_t)4 * 16 * 1024;

  unsigned short* ws_us = (unsigned short*)d_ws;
  unsigned short* x_bf    = ws_us;                             // 4M elems
  unsigned short* wa_bf   = x_bf + (size_t)4 * 1024 * 1024;    // 3M
  unsigned short* wp_bf   = wa_bf + (size_t)3 * 1024 * 1024;   // 1M
  unsigned short* qkv_bf  = wp_bf + (size_t)1024 * 1024;       // 12M
  unsigned short* yatt_bf = qkv_bf + (size_t)4096 * 3072;      // 4M
  unsigned short* pbits   = yatt_bf + (size_t)4096 * 1024;     // 4M u16 = 8MB

  dim3 blk(256);
  cvt3_bf16<<<dim3(8192), blk, 0, stream>>>((const float4*)x, (const float4*)w_attn,
                                            (const float4*)w_proj, (uint2*)x_bf);
  gemm_bf16<1><<<dim3(32, 24), blk, 0, stream>>>(x_bf, wa_bf, (void*)qkv_bf, 4096, 3072, 1024);
  attn_sample<<<dim3(8704), blk, 0, stream>>>(qkv_bf, pbits);
  attn_pv<<<dim3(1024), blk, 0, stream>>>(qkv_bf, pbits, yatt_bf, attsum_out, attvar_out);
  gemm_bf16<0><<<dim3(32, 8), blk, 0, stream>>>(yatt_bf, wp_bf, (void*)y_out, 4096, 1024, 1024);
}